// Round 5
// baseline (909.710 us; speedup 1.0000x reference)
//
#include <hip/hip_runtime.h>
#include <math.h>

#define BB 128
#define SS 128
#define AE 65
#define VE 65
#define TE 129
#define PFD 128
#define FUSED 545025UL
#define FUSEDI 545025
#define VSTRIDE 136            // padded w-stride (multiple of 8)
#define APLANE 8840            // 65*136
#define FPP 574976UL           // padded per-b f16 row stride = 65*8840 + 376 = 1123*512
#define FPPI 574976
#define KSP 512

typedef _Float16 half8 __attribute__((ext_vector_type(8)));
typedef float f32x16 __attribute__((ext_vector_type(16)));

// ---------------- zero-init accumulators ----------------
__global__ __launch_bounds__(256) void k_zero(float* __restrict__ p, int n) {
  int i = blockIdx.x * 256 + threadIdx.x;
  if (i < n) p[i] = 0.f;
}

// zero the pad holes of Fh: per (b,a,v) w=129..135, plus per-b tail [574600,574976)
__global__ __launch_bounds__(256) void k_fpad(_Float16* __restrict__ Fh) {
  const int b = blockIdx.x;
  _Float16* base = Fh + (size_t)b * FPP;
  for (int i = threadIdx.x; i < 29575; i += 256) {   // 65*455
    const int a = i / 455, r = i - a * 455;
    const int v = r / 7, e = r - v * 7;
    base[a * APLANE + v * VSTRIDE + 129 + e] = (_Float16)0.f;
  }
  for (int i = threadIdx.x; i < 376; i += 256) base[574600 + i] = (_Float16)0.f;
}

// ---------------- core: fusion[b][a][v][w], a>=1, v>=1, w=0..127 ----------------
// grid (BB, 32): a-pair = (1+2p, 2+2p). tv=tid>>4 (16 v-groups), tw=tid&15 (16 w-groups).
// per-thread: 2a x 4v x 8w; v = 1+4tv+i, w = 8tw+j (t' includes ones col at w=0).
__global__ __launch_bounds__(256) void k_core(
    const float* __restrict__ audio, const float* __restrict__ vision,
    const float* __restrict__ text, _Float16* __restrict__ Fh,
    float* __restrict__ normsq)
{
  const int b = blockIdx.x, p = blockIdx.y;
  const int tid = threadIdx.x;
  const int tw = tid & 15, tv = tid >> 4;

  __shared__ float sV[32][64];
  __shared__ float sT[32][136];
  __shared__ float sA[32][2];

  float acc[2][4][8];
#pragma unroll
  for (int aa = 0; aa < 2; ++aa)
#pragma unroll
    for (int i = 0; i < 4; ++i)
#pragma unroll
      for (int j = 0; j < 8; ++j) acc[aa][i][j] = 0.f;

  for (int c = 0; c < 4; ++c) {
    const int s0 = 32 * c;
    __syncthreads();
    const float* vb = &vision[(size_t)(b * SS + s0) * 64];
#pragma unroll
    for (int r = 0; r < 8; ++r) { const int e = tid + 256 * r; sV[e >> 6][e & 63] = vb[e]; }
    const float* tb = &text[(size_t)(b * SS + s0) * 128];
#pragma unroll
    for (int r = 0; r < 16; ++r) { const int e = tid + 256 * r; sT[e >> 7][1 + (e & 127)] = tb[e]; }
    if (tid < 32) sT[tid][0] = 1.f;
    if (tid >= 128 && tid < 192) {
      const int t2 = tid - 128, s = t2 >> 1, aa = t2 & 1;
      sA[s][aa] = audio[(size_t)(b * SS + s0 + s) * 64 + 2 * p + aa];
    }
    __syncthreads();
#pragma unroll 8
    for (int s = 0; s < 32; ++s) {
      const float2 ap = *(const float2*)&sA[s][0];
      const float4 vv = *(const float4*)&sV[s][4 * tv];
      const float4 t0 = *(const float4*)&sT[s][8 * tw];
      const float4 t1 = *(const float4*)&sT[s][8 * tw + 4];
      const float tt[8] = {t0.x, t0.y, t0.z, t0.w, t1.x, t1.y, t1.z, t1.w};
      const float vr[4] = {vv.x, vv.y, vv.z, vv.w};
#pragma unroll
      for (int i = 0; i < 4; ++i) {
        const float av0 = ap.x * vr[i];
        const float av1 = ap.y * vr[i];
#pragma unroll
        for (int j = 0; j < 8; ++j) {
          acc[0][i][j] += av0 * tt[j];
          acc[1][i][j] += av1 * tt[j];
        }
      }
    }
  }

  // ||.||^2 (a>=1,v>=1,w<=127 region)
  float ss = 0.f;
#pragma unroll
  for (int aa = 0; aa < 2; ++aa)
#pragma unroll
    for (int i = 0; i < 4; ++i)
#pragma unroll
      for (int j = 0; j < 8; ++j) ss += acc[aa][i][j] * acc[aa][i][j];
#pragma unroll
  for (int off = 32; off > 0; off >>= 1) ss += __shfl_down(ss, off);
  if ((tid & 63) == 0) atomicAdd(&normsq[b], ss);

  // direct aligned half8 stores (no barriers): byte offsets all ≡ 0 mod 16
#pragma unroll
  for (int aa = 0; aa < 2; ++aa) {
    const int a = 1 + 2 * p + aa;
    _Float16* Fb = Fh + (size_t)b * FPP + (size_t)a * APLANE;
#pragma unroll
    for (int i = 0; i < 4; ++i) {
      const int v = 1 + 4 * tv + i;
      half8 h;
#pragma unroll
      for (int j = 0; j < 8; ++j) h[j] = (_Float16)acc[aa][i][j];
      *(half8*)(Fb + (size_t)v * VSTRIDE + 8 * tw) = h;
    }
  }
}

// ---------------- plane a=0: v 0..64, w 0..128 ----------------
__global__ __launch_bounds__(256) void k_pa(
    const float* __restrict__ vision, const float* __restrict__ text,
    _Float16* __restrict__ Fh, float* __restrict__ normsq)
{
  const int b = blockIdx.x;
  const int tid = threadIdx.x;
  const int tw = tid & 15, tv = tid >> 4;
  __shared__ float sv[32][80];
  __shared__ float st[32][144];
  float acc[5][9];
#pragma unroll
  for (int i = 0; i < 5; ++i)
#pragma unroll
    for (int j = 0; j < 9; ++j) acc[i][j] = 0.f;

  for (int c = 0; c < 4; ++c) {
    const int s0 = 32 * c;
    __syncthreads();
    const float* vbase = &vision[((size_t)(b * SS + s0)) * 64];
#pragma unroll
    for (int r = 0; r < 8; ++r) {
      const int e = tid + 256 * r;
      sv[e >> 6][(e & 63) + 1] = vbase[e];
    }
    const float* tbase = &text[((size_t)(b * SS + s0)) * 128];
#pragma unroll
    for (int r = 0; r < 16; ++r) {
      const int e = tid + 256 * r;
      st[e >> 7][(e & 127) + 1] = tbase[e];
    }
    if (tid < 32) { sv[tid][0] = 1.f; st[tid][0] = 1.f; }
    __syncthreads();
    for (int s = 0; s < 32; ++s) {
      float vr[5], tr[9];
#pragma unroll
      for (int i = 0; i < 5; ++i) {
        const int vx = tv + 16 * i;
        vr[i] = (vx < VE) ? sv[s][vx] : 0.f;
      }
#pragma unroll
      for (int j = 0; j < 9; ++j) {
        const int wx = tw + 16 * j;
        tr[j] = (wx < TE) ? st[s][wx] : 0.f;
      }
#pragma unroll
      for (int i = 0; i < 5; ++i)
#pragma unroll
        for (int j = 0; j < 9; ++j) acc[i][j] += vr[i] * tr[j];
    }
  }
  _Float16* Fb = Fh + (size_t)b * FPP;   // a = 0
  float ss = 0.f;
#pragma unroll
  for (int i = 0; i < 5; ++i) {
    const int v = tv + 16 * i;
    if (v < VE) {
#pragma unroll
      for (int j = 0; j < 9; ++j) {
        const int w = tw + 16 * j;
        if (w < TE) {
          const float m = acc[i][j];
          Fb[(size_t)v * VSTRIDE + w] = (_Float16)m;
          ss += m * m;
        }
      }
    }
  }
#pragma unroll
  for (int off = 32; off > 0; off >>= 1) ss += __shfl_down(ss, off);
  if ((tid & 63) == 0) atomicAdd(&normsq[b], ss);
}

// ---------------- plane v=0: a 1..64, w 0..128 ----------------
__global__ __launch_bounds__(256) void k_pv(
    const float* __restrict__ audio, const float* __restrict__ text,
    _Float16* __restrict__ Fh, float* __restrict__ normsq)
{
  const int b = blockIdx.x;
  const int tid = threadIdx.x;
  const int tw = tid & 15, tv = tid >> 4;
  __shared__ float sa[32][64];
  __shared__ float st[32][144];
  float acc[4][9];
#pragma unroll
  for (int i = 0; i < 4; ++i)
#pragma unroll
    for (int j = 0; j < 9; ++j) acc[i][j] = 0.f;

  for (int c = 0; c < 4; ++c) {
    const int s0 = 32 * c;
    __syncthreads();
    const float* abase = &audio[((size_t)(b * SS + s0)) * 64];
#pragma unroll
    for (int r = 0; r < 8; ++r) {
      const int e = tid + 256 * r;
      sa[e >> 6][e & 63] = abase[e];
    }
    const float* tbase = &text[((size_t)(b * SS + s0)) * 128];
#pragma unroll
    for (int r = 0; r < 16; ++r) {
      const int e = tid + 256 * r;
      st[e >> 7][(e & 127) + 1] = tbase[e];
    }
    if (tid < 32) st[tid][0] = 1.f;
    __syncthreads();
    for (int s = 0; s < 32; ++s) {
      float ar[4], tr[9];
#pragma unroll
      for (int i = 0; i < 4; ++i) ar[i] = sa[s][tv + 16 * i];
#pragma unroll
      for (int j = 0; j < 9; ++j) {
        const int wx = tw + 16 * j;
        tr[j] = (wx < TE) ? st[s][wx] : 0.f;
      }
#pragma unroll
      for (int i = 0; i < 4; ++i)
#pragma unroll
        for (int j = 0; j < 9; ++j) acc[i][j] += ar[i] * tr[j];
    }
  }
  float ss = 0.f;
#pragma unroll
  for (int i = 0; i < 4; ++i) {
    const int a = 1 + tv + 16 * i;
    _Float16* Fb = Fh + (size_t)b * FPP + (size_t)a * APLANE;   // v = 0
#pragma unroll
    for (int j = 0; j < 9; ++j) {
      const int w = tw + 16 * j;
      if (w < TE) {
        const float m = acc[i][j];
        Fb[w] = (_Float16)m;
        ss += m * m;
      }
    }
  }
#pragma unroll
  for (int off = 32; off > 0; off >>= 1) ss += __shfl_down(ss, off);
  if ((tid & 63) == 0) atomicAdd(&normsq[b], ss);
}

// ---------------- column w=128: a 1..64, v 1..64 (weight t'[s][128]=text[..][127]) ----
__global__ __launch_bounds__(256) void k_wlast(
    const float* __restrict__ audio, const float* __restrict__ vision,
    const float* __restrict__ text, _Float16* __restrict__ Fh,
    float* __restrict__ Flast, float* __restrict__ normsq)
{
  const int b = blockIdx.x;
  const int tid = threadIdx.x;
  const int tw = tid & 15, tv = tid >> 4;
  __shared__ float sa[32][64];
  __shared__ float sv[32][64];
  __shared__ float swt[32];
  float acc[4][4];
#pragma unroll
  for (int i = 0; i < 4; ++i)
#pragma unroll
    for (int j = 0; j < 4; ++j) acc[i][j] = 0.f;

  for (int c = 0; c < 4; ++c) {
    const int s0 = 32 * c;
    __syncthreads();
    const float* abase = &audio[((size_t)(b * SS + s0)) * 64];
    const float* vbase = &vision[((size_t)(b * SS + s0)) * 64];
#pragma unroll
    for (int r = 0; r < 8; ++r) {
      const int e = tid + 256 * r;
      sa[e >> 6][e & 63] = abase[e];
      sv[e >> 6][e & 63] = vbase[e];
    }
    if (tid < 32) swt[tid] = text[((size_t)(b * SS + s0 + tid)) * 128 + 127];
    __syncthreads();
    for (int s = 0; s < 32; ++s) {
      const float t = swt[s];
      float ar[4], vr[4];
#pragma unroll
      for (int i = 0; i < 4; ++i) ar[i] = sa[s][tv + 16 * i] * t;
#pragma unroll
      for (int j = 0; j < 4; ++j) vr[j] = sv[s][tw + 16 * j];
#pragma unroll
      for (int i = 0; i < 4; ++i)
#pragma unroll
        for (int j = 0; j < 4; ++j) acc[i][j] += ar[i] * vr[j];
    }
  }
  float ss = 0.f;
#pragma unroll
  for (int i = 0; i < 4; ++i) {
    const int a = 1 + tv + 16 * i;
    _Float16* Fb = Fh + (size_t)b * FPP + (size_t)a * APLANE;
#pragma unroll
    for (int j = 0; j < 4; ++j) {
      const int v = 1 + tw + 16 * j;
      float m = acc[i][j];
      ss += m * m;
      if (a == 64 && v == 64) { Flast[b] = m; m = 0.f; }  // exact fp32 path via k_final
      Fb[(size_t)v * VSTRIDE + 128] = (_Float16)m;
    }
  }
#pragma unroll
  for (int off = 32; off > 0; off >>= 1) ss += __shfl_down(ss, off);
  if ((tid & 63) == 0) atomicAdd(&normsq[b], ss);
}

// ---------------- deep-K MFMA GEMM, no LDS, no barriers ----------------
// grid 1123 (padded-K split, KSP=512). 4 waves; wave wv owns p-rows [32wv,32wv+32), all 128 b.
// A: W1 f32 loaded per-lane (8 dwords) + cvt f16. B: Fh half8 direct. Padded-k -> W1-k via
// incremental (w,ko) tracker; pad holes have F==0 so clamped/mismatched W1 reads contribute 0.
__global__ __launch_bounds__(256) void k_gemm(
    const float* __restrict__ W1, const _Float16* __restrict__ Fh,
    float* __restrict__ y1pre)
{
  const int tid = threadIdx.x;
  const int wv = tid >> 6;
  const int ln = tid & 63, lb = ln & 31, hb = ln >> 5;
  const int p = (wv << 5) + lb;                 // lane's A-row (W1 row)
  const int kp0 = blockIdx.x * KSP + (hb << 3); // lane's first padded-k

  int a = kp0 / APLANE;
  int r = kp0 - a * APLANE;
  int v = r / VSTRIDE;
  int w = r - v * VSTRIDE;
  int ko = a * 8385 + v * 129 + w;              // matching W1 k-index

  const float* wrow = W1 + (size_t)p * FUSED;
  const _Float16* fb0 = Fh + (size_t)lb * FPP + kp0;
  const _Float16* fb1 = fb0 + (size_t)32 * FPP;
  const _Float16* fb2 = fb0 + (size_t)64 * FPP;
  const _Float16* fb3 = fb0 + (size_t)96 * FPP;

  f32x16 acc0 = {}, acc1 = {}, acc2 = {}, acc3 = {};

#pragma unroll 8
  for (int step = 0; step < 32; ++step) {
    const int kc = (ko > 545016) ? 545008 : ko;  // safety clamp; only hits where F==0
    half8 af;
#pragma unroll
    for (int e = 0; e < 8; ++e) af[e] = (_Float16)wrow[kc + e];
    const int off = step << 4;
    const half8 b0 = *(const half8*)(fb0 + off);
    const half8 b1 = *(const half8*)(fb1 + off);
    const half8 b2 = *(const half8*)(fb2 + off);
    const half8 b3 = *(const half8*)(fb3 + off);
    acc0 = __builtin_amdgcn_mfma_f32_32x32x16_f16(af, b0, acc0, 0, 0, 0);
    acc1 = __builtin_amdgcn_mfma_f32_32x32x16_f16(af, b1, acc1, 0, 0, 0);
    acc2 = __builtin_amdgcn_mfma_f32_32x32x16_f16(af, b2, acc2, 0, 0, 0);
    acc3 = __builtin_amdgcn_mfma_f32_32x32x16_f16(af, b3, acc3, 0, 0, 0);
    w += 16;
    if (w >= VSTRIDE) { w -= VSTRIDE; ko += 9; } else { ko += 16; }
  }

  // drain: C col=lane&31 (b-local), row=(reg&3)+8*(reg>>2)+4*hb (p-local within wave tile)
#pragma unroll
  for (int reg = 0; reg < 16; ++reg) {
    const int prow = (reg & 3) + 8 * (reg >> 2) + 4 * hb;
    const int pp = (wv << 5) + prow;
    atomicAdd(&y1pre[(size_t)lb * PFD + pp], acc0[reg]);
    atomicAdd(&y1pre[(size_t)(32 + lb) * PFD + pp], acc1[reg]);
    atomicAdd(&y1pre[(size_t)(64 + lb) * PFD + pp], acc2[reg]);
    atomicAdd(&y1pre[(size_t)(96 + lb) * PFD + pp], acc3[reg]);
  }
}

// ---------------- finalize: MLP per batch ----------------
__global__ __launch_bounds__(128) void k_final(
    const float* __restrict__ y1pre, const float* __restrict__ b1,
    const float* __restrict__ W2, const float* __restrict__ b2,
    const float* __restrict__ W3, const float* __restrict__ b3,
    const float* __restrict__ W1, const float* __restrict__ Flast,
    float* __restrict__ out)
{
  const int b = blockIdx.x, p = threadIdx.x;
  __shared__ float y1[PFD];
  __shared__ float red[PFD];
  const float extra = W1[(size_t)p * FUSED + (FUSED - 1)] * Flast[b];
  y1[p] = fmaxf(y1pre[(size_t)b * PFD + p] + extra + b1[p], 0.f);
  __syncthreads();
  float s = b2[p];
  for (int k = 0; k < PFD; ++k) s += y1[k] * W2[p * PFD + k];
  const float y2 = fmaxf(s, 0.f);
  red[p] = y2 * W3[p];
  __syncthreads();
  for (int off = 64; off > 0; off >>= 1) {
    if (p < off) red[p] += red[p + off];
    __syncthreads();
  }
  if (p == 0) {
    const float x = red[0] + b3[0];
    out[b] = 6.f / (1.f + expf(-x)) - 3.f;
  }
}

__global__ __launch_bounds__(128) void k_reg(const float* __restrict__ normsq,
                                             float* __restrict__ out)
{
  const int t = threadIdx.x;
  __shared__ float red[BB];
  red[t] = sqrtf(normsq[t]);
  __syncthreads();
  for (int off = 64; off > 0; off >>= 1) {
    if (t < off) red[t] += red[t + off];
    __syncthreads();
  }
  // tmp = sqrt(64*64*128/128) = 64 exactly; mean over B
  if (t == 0) out[BB] = 64.f * red[0] / (float)BB;
}

extern "C" void kernel_launch(void* const* d_in, const int* in_sizes, int n_in,
                              void* d_out, int out_size, void* d_ws, size_t ws_size,
                              hipStream_t stream) {
  const float* audio  = (const float*)d_in[0];
  const float* vision = (const float*)d_in[1];
  const float* text   = (const float*)d_in[2];
  const float* W1     = (const float*)d_in[3];
  const float* b1     = (const float*)d_in[4];
  const float* W2     = (const float*)d_in[5];
  const float* b2     = (const float*)d_in[6];
  const float* W3     = (const float*)d_in[7];
  const float* b3     = (const float*)d_in[8];
  float* out = (float*)d_out;

  // ws layout (proven bound ws >= 279,183,872 B):
  // [y1pre 64KB][normsq 512B][Flast 512B] ... Fh (f16, padded) at +128KB: 147,193,856 B
  float* y1pre  = (float*)d_ws;
  float* normsq = y1pre + BB * PFD;
  float* Flast  = normsq + BB;
  _Float16* Fh = (_Float16*)((char*)d_ws + 131072);

  k_zero<<<65, 256, 0, stream>>>(y1pre, BB * PFD + 2 * BB);
  k_fpad<<<BB, 256, 0, stream>>>(Fh);

  k_core<<<dim3(BB, 32), 256, 0, stream>>>(audio, vision, text, Fh, normsq);
  k_pa<<<BB, 256, 0, stream>>>(vision, text, Fh, normsq);
  k_pv<<<BB, 256, 0, stream>>>(audio, text, Fh, normsq);
  k_wlast<<<BB, 256, 0, stream>>>(audio, vision, text, Fh, Flast, normsq);

  k_gemm<<<FPPI / KSP, 256, 0, stream>>>(W1, Fh, y1pre);   // 1123 blocks

  k_final<<<BB, PFD, 0, stream>>>(y1pre, b1, W2, b2, W3, b3, W1, Flast, out);
  k_reg<<<1, BB, 0, stream>>>(normsq, out);
}